// Round 4
// baseline (125.554 us; speedup 1.0000x reference)
//
#include <hip/hip_runtime.h>

// Problem dims (fixed by setup_inputs): feat [B,H,W,D,F] float32
#define BB 32
#define HH 128
#define WW 128
#define DD 16
#define FF 8
#define VEC_PER_ROW 32              // DD*FF floats = 32 float4 per (b,h,w) row
#define HW (HH * WW)
#define PLANE_VEC (HW * VEC_PER_ROW)      // 524288 float4 per batch plane

#define GRID 2048
#define BLK  256
// GRID*BLK == PLANE_VEC: each thread owns one (h,w,k) slot across all 32 batches.

// native vector type (HIP_vector_type rejects some builtins; this is plain)
typedef float f32x4 __attribute__((ext_vector_type(4)));

// ---------------------------------------------------------------------------
// Kernel 1: build the (h,w)->source-row map. One entry per output (h,w):
//   map[h*W+w] = yi*W + xi  (source plane row index) or -1 if rotation-invalid.
// Composition (output -> input): flip2 -> roll -> rotate.
// Float math replicates the reference EXACTLY: double trig cast to f32,
// pure f32 mul/add (no FMA contraction), rintf = round-half-even (np.round).
// ---------------------------------------------------------------------------
__global__ void build_map_kernel(const int* __restrict__ rot_deg,
                                 const int* __restrict__ shift_h,
                                 const int* __restrict__ shift_w,
                                 const int* __restrict__ flip2,
                                 int* __restrict__ map) {
    int idx = blockIdx.x * blockDim.x + threadIdx.x;
    if (idx >= HW) return;
    int h = idx >> 7;
    int w = idx & (WW - 1);

    int sh = *shift_h;
    int sw = *shift_w;
    int f2 = *flip2;

    double th = (double)(*rot_deg) * (3.14159265358979323846 / 180.0);
    float c = (float)cos(th);
    float s = (float)sin(th);
    const float xc = (float)(WW - 1) * 0.5f;
    const float yc = (float)(HH - 1) * 0.5f;

    int i  = (h - sh) & (HH - 1);              // inverse roll (rows)
    int w1 = f2 ? (WW - 1 - w) : w;            // inverse flip (cols)
    int j  = (w1 - sw) & (WW - 1);             // inverse roll (cols)

    float dx = (float)j - xc;
    float dy = (float)i - yc;
    float xs = __fadd_rn(__fadd_rn(__fmul_rn(c, dx), __fmul_rn(s, dy)), xc);
    float ys = __fadd_rn(__fadd_rn(__fmul_rn(-s, dx), __fmul_rn(c, dy)), yc);
    int xi = (int)rintf(xs);
    int yi = (int)rintf(ys);
    bool valid = (xi >= 0) && (xi < WW) && (yi >= 0) && (yi < HH);
    map[idx] = valid ? (yi * WW + xi) : -1;
}

// ---------------------------------------------------------------------------
// Kernel 2: row gather, h-FAST thread assignment.
//   tid -> k = tid&31, h = (tid>>5)&127, w = tid>>12
// A wave (64 lanes) covers output rows (h,w) and (h+1,w):
//   reads : src rows step ~cos80deg*512B + sin80deg*row ~= +504B  -> ~1KB
//           nearly-contiguous read stream per wave (latency-friendly)
//   writes: 2 x 512B chunks 64KB apart (posted, aggregate in L2)
// map/k/flip3 math hoisted; b-loop is a pure 8MB-stride copy, unroll x4,
// loads batched before stores. Invalid rows: zero-store, reads skipped.
// ---------------------------------------------------------------------------
__global__ void __launch_bounds__(BLK)
gather_kernel(const f32x4* __restrict__ src,
              f32x4* __restrict__ dst,
              const int* __restrict__ map,
              const int* __restrict__ flip3) {
    const int tid = blockIdx.x * BLK + (int)threadIdx.x;   // [0, PLANE_VEC)
    const int k = tid & (VEC_PER_ROW - 1);
    const int h = (tid >> 5) & (HH - 1);
    const int w = tid >> 12;
    const int hw = (h << 7) | w;          // output plane row index
    const int m = map[hw];

    f32x4* __restrict__ d = dst + ((size_t)hw << 5) + (size_t)k;

    if (m >= 0) {
        const int f3 = *flip3;
        // flip3 reverses D (16 slots of 2 float4) within the row
        const int kk = f3 ? ((((DD - 1) - (k >> 1)) << 1) | (k & 1)) : k;
        const f32x4* __restrict__ s = src + ((size_t)m << 5) + (size_t)kk;
        #pragma unroll
        for (int b = 0; b < BB; b += 4) {
            f32x4 v0 = s[(size_t)(b + 0) * PLANE_VEC];
            f32x4 v1 = s[(size_t)(b + 1) * PLANE_VEC];
            f32x4 v2 = s[(size_t)(b + 2) * PLANE_VEC];
            f32x4 v3 = s[(size_t)(b + 3) * PLANE_VEC];
            d[(size_t)(b + 0) * PLANE_VEC] = v0;
            d[(size_t)(b + 1) * PLANE_VEC] = v1;
            d[(size_t)(b + 2) * PLANE_VEC] = v2;
            d[(size_t)(b + 3) * PLANE_VEC] = v3;
        }
    } else {
        const f32x4 z = (f32x4){0.f, 0.f, 0.f, 0.f};
        #pragma unroll
        for (int b = 0; b < BB; ++b)
            d[(size_t)b * PLANE_VEC] = z;
    }
}

extern "C" void kernel_launch(void* const* d_in, const int* in_sizes, int n_in,
                              void* d_out, int out_size, void* d_ws, size_t ws_size,
                              hipStream_t stream) {
    const float* feat = (const float*)d_in[0];
    const int* rot    = (const int*)d_in[1];
    const int* sh     = (const int*)d_in[2];
    const int* sw     = (const int*)d_in[3];
    const int* f2     = (const int*)d_in[4];
    const int* f3     = (const int*)d_in[5];
    float* out = (float*)d_out;

    int* map = (int*)d_ws;   // 64 KB; ws proven sufficient in round 1
    build_map_kernel<<<(HW + 255) / 256, 256, 0, stream>>>(rot, sh, sw, f2, map);
    gather_kernel<<<GRID, BLK, 0, stream>>>((const f32x4*)feat, (f32x4*)out, map, f3);
}

// Round 5
// 108.839 us; speedup vs baseline: 1.1536x; 1.1536x over previous
//
#include <hip/hip_runtime.h>

// Problem dims (fixed by setup_inputs): feat [B,H,W,D,F] float32
#define BB 32
#define HH 128
#define WW 128
#define DD 16
#define FF 8
#define VEC_PER_ROW 32              // DD*FF floats = 32 float4 per (b,h,w) row
#define HW (HH * WW)
#define PLANE_VEC (HW * VEC_PER_ROW)      // 524288 float4 per batch plane (2^19)
#define TOTAL_VEC (BB * PLANE_VEC)        // 2^24

// Each thread moves 4 float4s: planes b0, b0+8, b0+16, b0+24 at one (hw,k) slot.
// Threads = 8 * PLANE_VEC = 2^22 -> grid 16384 blocks = 8x resident capacity
// (2048). Early-retiring zero-work blocks are replaced by the dispatcher ->
// dynamic load balancing across the ~30% rotation-invalid region.
#define BLK  256
#define GRID (8 * PLANE_VEC / BLK)        // 16384

typedef float f32x4 __attribute__((ext_vector_type(4)));

// ---------------------------------------------------------------------------
// Kernel 1: build the (h,w)->source-row map. One entry per output (h,w):
//   map[h*W+w] = yi*W + xi  (source plane row index) or -1 if rotation-invalid.
// Composition (output -> input): flip2 -> roll -> rotate.
// Float math replicates the reference EXACTLY: double trig cast to f32,
// pure f32 mul/add (no FMA contraction), rintf = round-half-even (np.round).
// ---------------------------------------------------------------------------
__global__ void build_map_kernel(const int* __restrict__ rot_deg,
                                 const int* __restrict__ shift_h,
                                 const int* __restrict__ shift_w,
                                 const int* __restrict__ flip2,
                                 int* __restrict__ map) {
    int idx = blockIdx.x * blockDim.x + threadIdx.x;
    if (idx >= HW) return;
    int h = idx >> 7;
    int w = idx & (WW - 1);

    int sh = *shift_h;
    int sw = *shift_w;
    int f2 = *flip2;

    double th = (double)(*rot_deg) * (3.14159265358979323846 / 180.0);
    float c = (float)cos(th);
    float s = (float)sin(th);
    const float xc = (float)(WW - 1) * 0.5f;
    const float yc = (float)(HH - 1) * 0.5f;

    int i  = (h - sh) & (HH - 1);              // inverse roll (rows)
    int w1 = f2 ? (WW - 1 - w) : w;            // inverse flip (cols)
    int j  = (w1 - sw) & (WW - 1);             // inverse roll (cols)

    float dx = (float)j - xc;
    float dy = (float)i - yc;
    float xs = __fadd_rn(__fadd_rn(__fmul_rn(c, dx), __fmul_rn(s, dy)), xc);
    float ys = __fadd_rn(__fadd_rn(__fmul_rn(-s, dx), __fmul_rn(c, dy)), yc);
    int xi = (int)rintf(xs);
    int yi = (int)rintf(ys);
    bool valid = (xi >= 0) && (xi < WW) && (yi >= 0) && (yi < HH);
    map[idx] = valid ? (yi * WW + xi) : -1;
}

// ---------------------------------------------------------------------------
// Kernel 2: row gather, output-linear within plane (fully coalesced writes),
// 4 planes per thread (4-deep MLP), 8x oversubscribed grid for dynamic
// balancing of the zero-work (rotation-invalid) region.
//   t in [0, 8*PLANE_VEC): k = t&31, hw = (t>>5)&16383, b0 = t>>19 in [0,8)
//   planes handled: b0 + 8*u, u = 0..3
// ---------------------------------------------------------------------------
__global__ void __launch_bounds__(BLK)
gather_kernel(const f32x4* __restrict__ src,
              f32x4* __restrict__ dst,
              const int* __restrict__ map,
              const int* __restrict__ flip3) {
    const int t  = blockIdx.x * BLK + (int)threadIdx.x;   // [0, 8*PLANE_VEC)
    const int k  = t & (VEC_PER_ROW - 1);
    const int hw = (t >> 5) & (HW - 1);
    const int b0 = t >> 19;                               // [0, 8)
    const int m  = map[hw];

    const size_t slot = ((size_t)hw << 5) + (size_t)k;    // float4 index in plane
    f32x4* __restrict__ d = dst + ((size_t)b0 << 19) + slot;

    if (m >= 0) {
        const int f3 = *flip3;
        // flip3 reverses D (16 slots of 2 float4) within the row
        const int kk = f3 ? ((((DD - 1) - (k >> 1)) << 1) | (k & 1)) : k;
        const f32x4* __restrict__ s =
            src + ((size_t)b0 << 19) + ((size_t)m << 5) + (size_t)kk;
        f32x4 v0 = s[(size_t)(8 * 0) * PLANE_VEC];
        f32x4 v1 = s[(size_t)(8 * 1) * PLANE_VEC];
        f32x4 v2 = s[(size_t)(8 * 2) * PLANE_VEC];
        f32x4 v3 = s[(size_t)(8 * 3) * PLANE_VEC];
        d[(size_t)(8 * 0) * PLANE_VEC] = v0;
        d[(size_t)(8 * 1) * PLANE_VEC] = v1;
        d[(size_t)(8 * 2) * PLANE_VEC] = v2;
        d[(size_t)(8 * 3) * PLANE_VEC] = v3;
    } else {
        const f32x4 z = (f32x4){0.f, 0.f, 0.f, 0.f};
        d[(size_t)(8 * 0) * PLANE_VEC] = z;
        d[(size_t)(8 * 1) * PLANE_VEC] = z;
        d[(size_t)(8 * 2) * PLANE_VEC] = z;
        d[(size_t)(8 * 3) * PLANE_VEC] = z;
    }
}

extern "C" void kernel_launch(void* const* d_in, const int* in_sizes, int n_in,
                              void* d_out, int out_size, void* d_ws, size_t ws_size,
                              hipStream_t stream) {
    const float* feat = (const float*)d_in[0];
    const int* rot    = (const int*)d_in[1];
    const int* sh     = (const int*)d_in[2];
    const int* sw     = (const int*)d_in[3];
    const int* f2     = (const int*)d_in[4];
    const int* f3     = (const int*)d_in[5];
    float* out = (float*)d_out;

    int* map = (int*)d_ws;   // 64 KB; ws proven sufficient
    build_map_kernel<<<(HW + 255) / 256, 256, 0, stream>>>(rot, sh, sw, f2, map);
    gather_kernel<<<GRID, BLK, 0, stream>>>((const f32x4*)feat, (f32x4*)out, map, f3);
}